// Round 12
// baseline (49.595 us; speedup 1.0000x reference)
//
#include <hip/hip_runtime.h>
#include <math.h>

// LinearAttention3D, B=2, C=64, N = 128*128*16 = 262144, HEADS=2, DIM_HEAD=1.
// softmax over dim_head (size 1) == 1.0, SCALE == 1.0 -> q/query/W_q are dead.
// out[b,o,n] = W_out[o,:] . ctx[b,:] + b_out[o] (constant over n), where
// ctx[b,h] = (sum_n e^{k_h(n)} v_h(n)) / (sum_n e^{k_h(n)}).
// |k| <~ 5 so unstabilized fp32 exp-sums are safe -> combine is a plain add.
//
// Lessons: agent-scope fences/atomics in hot kernels catastrophic (R5/R6/R8);
// nt-stores regress (R9); batch-pipeline neutral (R10); 1KB wave-loads ~neutral
// (R11). THIS round: longer DRAM runs — each wave owns 16 channels and reads
// 2 consecutive 1KB lines per channel (2KB sequential runs); cross-wave
// channel-partial combine via 32KB LDS tile. Fewer k1 blocks (512/batch),
// fewer partials (k2 prelude halved).

#define C_IN 64
#define COLS 65536                 // float4 columns per batch
#define BLK  256
#define NB1  512                   // k1 blocks per batch (1024 total)
#define CPB  128                   // float4-cols per k1 block (2KB wide)
#define GRID2 1024
#define F4_PER_BLK 8192            // out float4 per k2 block (8388608 / 1024)

// ---------------- Pass 1: fused k/v projection + exp-sum partial reduction ---
// grid (NB1, 2), block 256 = 4 waves. Block tile: 64 channels x 128 float4-cols.
// Wave w owns channels [16w,16w+16); per channel it reads 2 consecutive 1KB
// lines (cols col0..col0+127) -> 2KB sequential run. Dots are 16-channel
// partials per wave; combined across waves via LDS, then exp+reduce.
__global__ __launch_bounds__(BLK) void k1_proj_reduce(
    const float* __restrict__ x, const float* __restrict__ Wqkv,
    float4* __restrict__ partials /* [2][NB1] of {s0, sv0, s1, sv1} */)
{
    __shared__ float  s_w[4][C_IN];        // W_qkv rows 2..5: k0, k1, v0, v1
    __shared__ float4 s_part[4][2][4][64]; // [quantity][jhalf][wave][lane] 32KB
    __shared__ float4 s_red[2];
    const int tid = threadIdx.x;
    const int b = blockIdx.y;

    s_w[tid >> 6][tid & 63] = Wqkv[(2 + (tid >> 6)) * C_IN + (tid & 63)];
    __syncthreads();

    const int wave = tid >> 6;
    const int lane = tid & 63;
    const int col0 = blockIdx.x * CPB;

    // this wave's first channel row, at this lane's position
    const float4* xp = reinterpret_cast<const float4*>(x)
                       + (size_t)b * C_IN * COLS + (size_t)(wave << 4) * COLS
                       + col0 + lane;

    float4 k0a = make_float4(0.f, 0.f, 0.f, 0.f);
    float4 k0b = k0a, k1a = k0a, k1b = k0a;
    float4 v0a = k0a, v0b = k0a, v1a = k0a, v1b = k0a;

    #pragma unroll
    for (int c = 0; c < 16; ++c) {
        const float4* row = xp + (size_t)c * COLS;
        float4 xa = row[0];                  // cols [col0, col0+64)   : 1KB
        float4 xb = row[64];                 // cols [col0+64, col0+128): next 1KB
        const int ch = (wave << 4) + c;
        float wk0 = s_w[0][ch], wk1 = s_w[1][ch];
        float wv0 = s_w[2][ch], wv1 = s_w[3][ch];
        k0a.x = fmaf(xa.x, wk0, k0a.x); k0a.y = fmaf(xa.y, wk0, k0a.y);
        k0a.z = fmaf(xa.z, wk0, k0a.z); k0a.w = fmaf(xa.w, wk0, k0a.w);
        k0b.x = fmaf(xb.x, wk0, k0b.x); k0b.y = fmaf(xb.y, wk0, k0b.y);
        k0b.z = fmaf(xb.z, wk0, k0b.z); k0b.w = fmaf(xb.w, wk0, k0b.w);
        k1a.x = fmaf(xa.x, wk1, k1a.x); k1a.y = fmaf(xa.y, wk1, k1a.y);
        k1a.z = fmaf(xa.z, wk1, k1a.z); k1a.w = fmaf(xa.w, wk1, k1a.w);
        k1b.x = fmaf(xb.x, wk1, k1b.x); k1b.y = fmaf(xb.y, wk1, k1b.y);
        k1b.z = fmaf(xb.z, wk1, k1b.z); k1b.w = fmaf(xb.w, wk1, k1b.w);
        v0a.x = fmaf(xa.x, wv0, v0a.x); v0a.y = fmaf(xa.y, wv0, v0a.y);
        v0a.z = fmaf(xa.z, wv0, v0a.z); v0a.w = fmaf(xa.w, wv0, v0a.w);
        v0b.x = fmaf(xb.x, wv0, v0b.x); v0b.y = fmaf(xb.y, wv0, v0b.y);
        v0b.z = fmaf(xb.z, wv0, v0b.z); v0b.w = fmaf(xb.w, wv0, v0b.w);
        v1a.x = fmaf(xa.x, wv1, v1a.x); v1a.y = fmaf(xa.y, wv1, v1a.y);
        v1a.z = fmaf(xa.z, wv1, v1a.z); v1a.w = fmaf(xa.w, wv1, v1a.w);
        v1b.x = fmaf(xb.x, wv1, v1b.x); v1b.y = fmaf(xb.y, wv1, v1b.y);
        v1b.z = fmaf(xb.z, wv1, v1b.z); v1b.w = fmaf(xb.w, wv1, v1b.w);
    }

    // stash 16-channel partials; [q][j][w] fixed -> lanes write consecutive
    // 16B -> conflict-free.
    s_part[0][0][wave][lane] = k0a; s_part[0][1][wave][lane] = k0b;
    s_part[1][0][wave][lane] = k1a; s_part[1][1][wave][lane] = k1b;
    s_part[2][0][wave][lane] = v0a; s_part[2][1][wave][lane] = v0b;
    s_part[3][0][wave][lane] = v1a; s_part[3][1][wave][lane] = v1b;
    __syncthreads();

    // waves 0,1: combine 4 wave-partials (full 64-ch dots) for j-half = wave,
    // then exp + butterfly over the 64 lanes.
    if (wave < 2) {
        const int j = wave;
        float4 p0, p1, p2, p3;
        p0 = s_part[0][j][0][lane]; p1 = s_part[0][j][1][lane];
        p2 = s_part[0][j][2][lane]; p3 = s_part[0][j][3][lane];
        float4 K0 = make_float4(p0.x + p1.x + p2.x + p3.x,
                                p0.y + p1.y + p2.y + p3.y,
                                p0.z + p1.z + p2.z + p3.z,
                                p0.w + p1.w + p2.w + p3.w);
        p0 = s_part[1][j][0][lane]; p1 = s_part[1][j][1][lane];
        p2 = s_part[1][j][2][lane]; p3 = s_part[1][j][3][lane];
        float4 K1 = make_float4(p0.x + p1.x + p2.x + p3.x,
                                p0.y + p1.y + p2.y + p3.y,
                                p0.z + p1.z + p2.z + p3.z,
                                p0.w + p1.w + p2.w + p3.w);
        p0 = s_part[2][j][0][lane]; p1 = s_part[2][j][1][lane];
        p2 = s_part[2][j][2][lane]; p3 = s_part[2][j][3][lane];
        float4 V0 = make_float4(p0.x + p1.x + p2.x + p3.x,
                                p0.y + p1.y + p2.y + p3.y,
                                p0.z + p1.z + p2.z + p3.z,
                                p0.w + p1.w + p2.w + p3.w);
        p0 = s_part[3][j][0][lane]; p1 = s_part[3][j][1][lane];
        p2 = s_part[3][j][2][lane]; p3 = s_part[3][j][3][lane];
        float4 V1 = make_float4(p0.x + p1.x + p2.x + p3.x,
                                p0.y + p1.y + p2.y + p3.y,
                                p0.z + p1.z + p2.z + p3.z,
                                p0.w + p1.w + p2.w + p3.w);

        // Unstabilized exp-sums (safe: |k| <~ 5).
        float s0 = 0.f, sv0 = 0.f, s1 = 0.f, sv1 = 0.f;
        float e;
        e = __expf(K0.x); s0 += e; sv0 = fmaf(e, V0.x, sv0);
        e = __expf(K0.y); s0 += e; sv0 = fmaf(e, V0.y, sv0);
        e = __expf(K0.z); s0 += e; sv0 = fmaf(e, V0.z, sv0);
        e = __expf(K0.w); s0 += e; sv0 = fmaf(e, V0.w, sv0);
        e = __expf(K1.x); s1 += e; sv1 = fmaf(e, V1.x, sv1);
        e = __expf(K1.y); s1 += e; sv1 = fmaf(e, V1.y, sv1);
        e = __expf(K1.z); s1 += e; sv1 = fmaf(e, V1.z, sv1);
        e = __expf(K1.w); s1 += e; sv1 = fmaf(e, V1.w, sv1);

        #pragma unroll
        for (int off = 1; off <= 32; off <<= 1) {
            s0  += __shfl_xor(s0,  off);
            sv0 += __shfl_xor(sv0, off);
            s1  += __shfl_xor(s1,  off);
            sv1 += __shfl_xor(sv1, off);
        }
        if (lane == 0) s_red[j] = make_float4(s0, sv0, s1, sv1);
    }
    __syncthreads();
    if (tid == 0) {
        float4 r0 = s_red[0], r1 = s_red[1];
        partials[(size_t)b * NB1 + blockIdx.x] =
            make_float4(r0.x + r1.x, r0.y + r1.y, r0.z + r1.z, r0.w + r1.w);
    }
}

// ---------------- Pass 2: redundant per-block combine + plain fill -----------
// grid GRID2, block 256. Every block combines all partials in a FIXED order
// (deterministic, 16KB L2-hot), then fills its contiguous 128KB slice of out.
__global__ __launch_bounds__(BLK) void k2_combine_fill(
    const float* __restrict__ partials,
    const float* __restrict__ Wout,
    const float* __restrict__ bout,
    float* __restrict__ out)
{
    __shared__ float s_ctx[2][2];
    const int tid = threadIdx.x;
    const int wave = tid >> 6, lane = tid & 63;
    const int b = wave >> 1, h = wave & 1;

    // wave (b,h): sum 512 partial (s, sv) pairs, lane-strided + butterfly.
    const float2* p2 = reinterpret_cast<const float2*>(partials);
    float s = 0.f, sv = 0.f;
    #pragma unroll
    for (int i = 0; i < NB1 / 64; ++i) {
        float2 t = p2[(size_t)(b * NB1 + i * 64 + lane) * 2 + h];
        s += t.x; sv += t.y;
    }
    #pragma unroll
    for (int off = 1; off <= 32; off <<= 1) {
        s  += __shfl_xor(s,  off);
        sv += __shfl_xor(sv, off);
    }
    if (lane == 0) s_ctx[b][h] = sv / s;
    __syncthreads();

    // This block's slice lies inside a single output row (8 blocks per row).
    const int row = blockIdx.x >> 3;            // b*64 + o
    const int bb = row >> 6, o = row & 63;
    const float v = fmaf(Wout[o * 2 + 0], s_ctx[bb][0],
                    fmaf(Wout[o * 2 + 1], s_ctx[bb][1], bout[o]));
    const float4 f4 = make_float4(v, v, v, v);

    float4* o4 = reinterpret_cast<float4*>(out);
    const size_t base = (size_t)blockIdx.x * F4_PER_BLK;
    #pragma unroll 8
    for (int k = 0; k < F4_PER_BLK / BLK; ++k)
        o4[base + ((size_t)k << 8) + tid] = f4;
}

extern "C" void kernel_launch(void* const* d_in, const int* in_sizes, int n_in,
                              void* d_out, int out_size, void* d_ws, size_t ws_size,
                              hipStream_t stream) {
    const float* x    = (const float*)d_in[0];
    // d_in[1] = query : dead (softmax over size-1 dim == 1)
    const float* Wqkv = (const float*)d_in[2];
    // d_in[3] = W_q   : dead
    const float* Wout = (const float*)d_in[4];
    const float* bout = (const float*)d_in[5];

    float4* partials = (float4*)d_ws;           // 2*512 float4 = 16 KB

    k1_proj_reduce<<<dim3(NB1, 2), BLK, 0, stream>>>(x, Wqkv, partials);
    k2_combine_fill<<<GRID2, BLK, 0, stream>>>((const float*)partials, Wout,
                                               bout, (float*)d_out);
}